// Round 4
// baseline (150.797 us; speedup 1.0000x reference)
//
#include <hip/hip_runtime.h>
#include <hip/hip_fp16.h>

#define FH 240
#define FW 240
#define NSAMP 179   // 9 + 49 + 121
constexpr float IMG = 960.0f;

// ---------------- ws layout (floats) ----------------
static constexpr int WS_FMT   = 0;        // fmT fp16 [240][240][64] -> 1,843,200 float slots
                                          // (dead after k_pool; reused as hcat [3n][64])
static constexpr int WS_GPART = 1843200;  // gpartial [960][64]
static constexpr int WS_G     = 1904640;  // g [64] (pre-scaled by 1/57600)
static constexpr int WS_PERM  = 1904704;  // perm [4000] ints
static constexpr int WS_POOL  = 1908736;  // pooled [3n][64] ; hidg [128] right after

// ---------- Kernel 1: blocks 0..959 transpose fm -> fp16 fmT + channel partials;
//                      block 960: counting-sort boxes by (cy,cx) buckets -> perm ----------
__global__ __launch_bounds__(256) void k_prep(const float* __restrict__ fm,
                                              __half* __restrict__ fmT,
                                              float* __restrict__ gpartial,
                                              const float* __restrict__ boxes,
                                              int* __restrict__ perm, int n) {
    __shared__ float tile[64][65];
    __shared__ float red[4][64];
    __shared__ int hist[256];
    __shared__ int offs[256];
    int bid = blockIdx.x;
    int tid = threadIdx.x;

    if (bid < 960) {
        int y  = bid >> 2;
        int x0 = (bid & 3) * 64;
        int lane = tid & 63;
        int wv   = tid >> 6;
        int x = x0 + lane;
        bool xin = (x < FW);
        #pragma unroll
        for (int k = 0; k < 16; ++k) {
            int c = wv + k * 4;
            tile[c][lane] = xin ? fm[c * (FH * FW) + y * FW + x] : 0.0f;
        }
        __syncthreads();

        {   // parallel channel-partial: 256 threads sum 16 each, then 64 combine
            int c = tid & 63, q = tid >> 6;
            float s = 0.0f;
            #pragma unroll
            for (int i = 0; i < 16; ++i) s += tile[c][q * 16 + i];
            red[q][c] = s;
        }

        #pragma unroll
        for (int it = 0; it < 2; ++it) {
            int idx = tid + it * 256;       // 0..511
            int xl  = idx >> 3;             // 0..63
            int co  = (idx & 7) * 8;        // 0,8,...,56
            int xx  = x0 + xl;
            if (xx < FW) {
                union { float4 f4; __half2 h2[4]; } u;
                #pragma unroll
                for (int i = 0; i < 4; ++i)
                    u.h2[i] = __floats2half2_rn(tile[co + 2*i][xl], tile[co + 2*i + 1][xl]);
                *(float4*)&fmT[((size_t)(y * FW + xx)) * 64 + co] = u.f4;
            }
        }
        __syncthreads();
        if (tid < 64)
            gpartial[bid * 64 + tid] = red[0][tid] + red[1][tid] + red[2][tid] + red[3][tid];
    } else {
        // ---- counting sort of boxes by (cy, cx) 16x16 buckets ----
        hist[tid] = 0;
        __syncthreads();
        for (int i = tid; i < n; i += 256) {
            float cy = (boxes[i * 4 + 1] + boxes[i * 4 + 3]) * 0.5f;
            float cx = (boxes[i * 4 + 0] + boxes[i * 4 + 2]) * 0.5f;
            int by = min(15, max(0, (int)(cy * (16.0f / 960.0f))));
            int bx = min(15, max(0, (int)(cx * (16.0f / 960.0f))));
            atomicAdd(&hist[by * 16 + bx], 1);
        }
        __syncthreads();
        offs[tid] = hist[tid];
        __syncthreads();
        for (int st = 1; st < 256; st <<= 1) {
            int t2 = (tid >= st) ? offs[tid - st] : 0;
            __syncthreads();
            offs[tid] += t2;
            __syncthreads();
        }
        hist[tid] = offs[tid] - hist[tid];     // exclusive start per bucket
        __syncthreads();
        for (int i = tid; i < n; i += 256) {
            float cy = (boxes[i * 4 + 1] + boxes[i * 4 + 3]) * 0.5f;
            float cx = (boxes[i * 4 + 0] + boxes[i * 4 + 2]) * 0.5f;
            int by = min(15, max(0, (int)(cy * (16.0f / 960.0f))));
            int bx = min(15, max(0, (int)(cx * (16.0f / 960.0f))));
            int pos = atomicAdd(&hist[by * 16 + bx], 1);
            perm[pos] = i;
        }
    }
}

// ---------- Kernel 2: ROI bilinear pooling ----------
// v4: balanced static slot partition (2/9/21 slots for the 3 scales, <=6 gather
// iters/slot, no idle slots), barriers 7 -> 2, single fused reduce, and XCD
// chunk swizzle so each XCD's L2 sees a contiguous run of (cy,cx)-sorted boxes.
__device__ __forceinline__ void acc8(float* a, const __half* __restrict__ base,
                                     int off, int c8, float w) {
    float4 raw = *(const float4*)(base + off + c8);   // 8 fp16
    const __half2* h = (const __half2*)&raw;
    #pragma unroll
    for (int i = 0; i < 4; ++i) {
        float2 f = __half22float2(h[i]);
        a[2*i]     = fmaf(w, f.x, a[2*i]);
        a[2*i + 1] = fmaf(w, f.y, a[2*i + 1]);
    }
}

__global__ __launch_bounds__(256) void k_pool(const __half* __restrict__ fmT,
                                              const float* __restrict__ boxes,
                                              const int* __restrict__ perm,
                                              const float* __restrict__ gpartial,
                                              float* __restrict__ g,
                                              float* __restrict__ pooled,
                                              const float* __restrict__ W1, const float* __restrict__ b1,
                                              const float* __restrict__ W2, const float* __restrict__ b2,
                                              const float* __restrict__ P1, const float* __restrict__ bp1,
                                              float* __restrict__ hidg) {
    __shared__ int   smp[NSAMP * 8];        // 5728 B
    __shared__ float part[64 * 33];         // 8448 B
    __shared__ float gsh[64];

    int tid = threadIdx.x;
    int nb  = gridDim.x;
    int bid = blockIdx.x;
    // XCD chunk swizzle (bijective only when nb % 8 == 0; else identity)
    int sbid = ((nb & 7) == 0) ? ((bid & 7) * (nb >> 3) + (bid >> 3)) : bid;

    if (bid == 0) {
        int c = tid & 63, q = tid >> 6;
        float s = 0.0f;
        for (int i = q * 240; i < q * 240 + 240; ++i) s += gpartial[i * 64 + c];
        part[tid] = s;
        __syncthreads();
        if (tid < 64) {
            float v = (part[tid] + part[64 + tid] + part[128 + tid] + part[192 + tid]) * (1.0f / 57600.0f);
            g[tid] = v;
            gsh[tid] = v;
        }
        __syncthreads();
    }

    int box = perm[sbid];

    // --- Phase 1: one thread per sample ---
    if (tid < NSAMP) {
        float bx1 = boxes[box * 4 + 0], by1 = boxes[box * 4 + 1];
        float bx2 = boxes[box * 4 + 2], by2 = boxes[box * 4 + 3];
        float x1n = (bx1 / IMG) * 2.0f - 1.0f;
        float y1n = (by1 / IMG) * 2.0f - 1.0f;
        float x2n = (bx2 / IMG) * 2.0f - 1.0f;
        float y2n = (by2 / IMG) * 2.0f - 1.0f;
        float cx = (x1n + x2n) * 0.5f, cy = (y1n + y2n) * 0.5f;
        float w2 = fmaxf(x2n - x1n, 1e-6f) * 0.5f;
        float h2 = fmaxf(y2n - y1n, 1e-6f) * 0.5f;
        int S, s, i;
        if (tid < 9)       { S = 3;  s = tid;      i = s / 3;  }
        else if (tid < 58) { S = 7;  s = tid - 9;  i = s / 7;  }
        else               { S = 11; s = tid - 58; i = s / 11; }
        int j = s - i * S;
        float Sf = (float)S;
        float bj = (2.0f * (float)j + 1.0f) / Sf - 1.0f;
        float bi = (2.0f * (float)i + 1.0f) / Sf - 1.0f;
        float gx = w2 * bj + cx;
        float gy = h2 * bi + cy;
        float ix = ((gx + 1.0f) * 240.0f - 1.0f) * 0.5f;
        float iy = ((gy + 1.0f) * 240.0f - 1.0f) * 0.5f;
        float x0f = floorf(ix), y0f = floorf(iy);
        float dx = ix - x0f,    dy = iy - y0f;
        int x0 = (int)x0f, y0 = (int)y0f;
        int x1 = x0 + 1,   y1 = y0 + 1;
        float inv = 1.0f / (Sf * Sf);
        float wx0 = (x0 >= 0 && x0 < FW) ? (1.0f - dx) : 0.0f;
        float wx1 = (x1 >= 0 && x1 < FW) ? dx          : 0.0f;
        float wy0 = (y0 >= 0 && y0 < FH) ? (1.0f - dy) : 0.0f;
        float wy1 = (y1 >= 0 && y1 < FH) ? dy          : 0.0f;
        int x0c = min(max(x0, 0), FW - 1), x1c = min(max(x1, 0), FW - 1);
        int y0c = min(max(y0, 0), FH - 1), y1c = min(max(y1, 0), FH - 1);
        int r0 = y0c * FW, r1 = y1c * FW;
        smp[tid * 8 + 0] = (r0 + x0c) * 64;
        smp[tid * 8 + 1] = (r0 + x1c) * 64;
        smp[tid * 8 + 2] = (r1 + x0c) * 64;
        smp[tid * 8 + 3] = (r1 + x1c) * 64;
        float* wp = (float*)&smp[tid * 8 + 4];
        wp[0] = wx0 * wy0 * inv;
        wp[1] = wx1 * wy0 * inv;
        wp[2] = wx0 * wy1 * inv;
        wp[3] = wx1 * wy1 * inv;
    }
    __syncthreads();

    // --- Phase 2: balanced gather. Slots 0-1: scale0 (9), 2-10: scale1 (49),
    //     11-31: scale2 (121). Every slot <=6 iterations, no barriers inside. ---
    {
        int slot = tid >> 3, l = tid & 7, c8 = l << 3;
        int start, stride, end;
        if (slot < 2)       { start = slot;           stride = 2;  end = 9;     }
        else if (slot < 11) { start = 9 + (slot - 2); stride = 9;  end = 58;    }
        else                { start = 58 + (slot - 11); stride = 21; end = NSAMP; }
        float a[8];
        #pragma unroll
        for (int k = 0; k < 8; ++k) a[k] = 0.0f;
        for (int s = start; s < end; s += stride) {
            int4   bo = *(const int4*)  &smp[s * 8];
            float4 wv = *(const float4*)&smp[s * 8 + 4];
            acc8(a, fmT, bo.x, c8, wv.x);
            acc8(a, fmT, bo.y, c8, wv.y);
            acc8(a, fmT, bo.z, c8, wv.z);
            acc8(a, fmT, bo.w, c8, wv.w);
        }
        #pragma unroll
        for (int i = 0; i < 8; ++i)
            part[(c8 + i) * 33 + slot] = a[i];
    }
    __syncthreads();

    // --- fused reduce: thread (sc,c) sums its scale's slot range ---
    if (tid < 192) {
        int sc = tid >> 6, c = tid & 63;
        int q0 = (sc == 0) ? 0 : (sc == 1) ? 2 : 11;
        int q1 = (sc == 0) ? 2 : (sc == 1) ? 11 : 32;
        float sum = 0.0f;
        for (int q = q0; q < q1; ++q) sum += part[c * 33 + q];
        pooled[(size_t)box * 192 + sc * 64 + c] = sum;
    }

    // ---- block 0 tail: g-head + fold its P1[192:256] contribution into hidg bias ----
    if (bid == 0) {
        __syncthreads();
        if (tid < 128) {                       // h1g = relu(g @ W1 + b1)
            float a = b1[tid];
            for (int k = 0; k < 64; ++k) a = fmaf(gsh[k], W1[k * 128 + tid], a);
            part[tid] = fmaxf(a, 0.0f);
        }
        __syncthreads();
        if (tid < 64) {                        // hg = relu(h1g @ W2 + b2)
            float a = b2[tid];
            for (int k = 0; k < 128; ++k) a = fmaf(part[k], W2[k * 64 + tid], a);
            part[128 + tid] = fmaxf(a, 0.0f);
        }
        __syncthreads();
        if (tid < 128) {                       // hidg = bp1 + hg @ P1[192:256]  (pre-relu bias)
            float a = bp1[tid];
            for (int k = 0; k < 64; ++k) a = fmaf(part[128 + k], P1[(192 + k) * 128 + tid], a);
            hidg[tid] = a;
        }
    }
}

// ---------- Kernel 3a: head GEMM over ALL rows (M = 3n = 12000) ----------
__global__ __launch_bounds__(256) void k_head(const float* __restrict__ pooled,
                                              const float* __restrict__ W1, const float* __restrict__ b1,
                                              const float* __restrict__ W2, const float* __restrict__ b2,
                                              float* __restrict__ hcat, int nrows) {
    __shared__ float x[16][68];
    __shared__ float h1[16][132];
    int tid = threadIdx.x;
    int row0 = blockIdx.x * 16;

    {   // stage x: 16 rows x 16 float4 = 256 -> one per thread
        int r = tid >> 4, q = (tid & 15) * 4;
        int gr = row0 + r;
        float4 v = make_float4(0, 0, 0, 0);
        if (gr < nrows) v = *(const float4*)&pooled[(size_t)gr * 64 + q];
        *(float4*)&x[r][q] = v;
    }
    __syncthreads();

    // ---- S1: h1 = relu(x @ W1 + b1)   [16x64]@[64x128] ----
    {
        int c4 = (tid & 31) * 4;           // 32 col-groups x 4 = 128
        int r2 = (tid >> 5) * 2;           // 8 row-groups x 2 = 16
        float acc[2][4] = {};
        #pragma unroll
        for (int k = 0; k < 64; k += 4) {
            float4 a0 = *(const float4*)&x[r2][k];
            float4 a1 = *(const float4*)&x[r2 + 1][k];
            #pragma unroll
            for (int kk = 0; kk < 4; ++kk) {
                float4 w = *(const float4*)&W1[(k + kk) * 128 + c4];
                float v0 = ((const float*)&a0)[kk];
                float v1 = ((const float*)&a1)[kk];
                acc[0][0] = fmaf(v0, w.x, acc[0][0]);
                acc[0][1] = fmaf(v0, w.y, acc[0][1]);
                acc[0][2] = fmaf(v0, w.z, acc[0][2]);
                acc[0][3] = fmaf(v0, w.w, acc[0][3]);
                acc[1][0] = fmaf(v1, w.x, acc[1][0]);
                acc[1][1] = fmaf(v1, w.y, acc[1][1]);
                acc[1][2] = fmaf(v1, w.z, acc[1][2]);
                acc[1][3] = fmaf(v1, w.w, acc[1][3]);
            }
        }
        float4 bb = *(const float4*)&b1[c4];
        #pragma unroll
        for (int rr = 0; rr < 2; ++rr) {
            float4 o;
            o.x = fmaxf(acc[rr][0] + bb.x, 0.0f);
            o.y = fmaxf(acc[rr][1] + bb.y, 0.0f);
            o.z = fmaxf(acc[rr][2] + bb.z, 0.0f);
            o.w = fmaxf(acc[rr][3] + bb.w, 0.0f);
            *(float4*)&h1[r2 + rr][c4] = o;
        }
    }
    __syncthreads();

    // ---- S2: h2 = relu(h1 @ W2 + b2) -> hcat   [16x128]@[128x64] ----
    {
        int c4 = (tid & 15) * 4;           // 16 col-groups x 4 = 64
        int r  = tid >> 4;                 // 16 rows
        float acc[4] = {};
        #pragma unroll
        for (int k = 0; k < 128; k += 4) {
            float4 a = *(const float4*)&h1[r][k];
            #pragma unroll
            for (int kk = 0; kk < 4; ++kk) {
                float4 w = *(const float4*)&W2[(k + kk) * 64 + c4];
                float av = ((const float*)&a)[kk];
                acc[0] = fmaf(av, w.x, acc[0]);
                acc[1] = fmaf(av, w.y, acc[1]);
                acc[2] = fmaf(av, w.z, acc[2]);
                acc[3] = fmaf(av, w.w, acc[3]);
            }
        }
        float4 bb = *(const float4*)&b2[c4];
        float4 o;
        o.x = fmaxf(acc[0] + bb.x, 0.0f);
        o.y = fmaxf(acc[1] + bb.y, 0.0f);
        o.z = fmaxf(acc[2] + bb.z, 0.0f);
        o.w = fmaxf(acc[3] + bb.w, 0.0f);
        int gr = row0 + r;
        if (gr < nrows)
            *(float4*)&hcat[(size_t)gr * 64 + c4] = o;
    }
}

// ---------- Kernel 3b: final MLP  out = relu(relu(hcat@P1[0:192] + hidg) @ P2 + bp2) ----------
__global__ __launch_bounds__(256) void k_tail(const float* __restrict__ hcat,
                                              const float* __restrict__ hidg,
                                              const float* __restrict__ P1,
                                              const float* __restrict__ P2, const float* __restrict__ bp2,
                                              float* __restrict__ out, int n) {
    __shared__ float ct[8][196];
    __shared__ float hid[8][132];
    int tid = threadIdx.x;
    int box0 = blockIdx.x * 8;

    // stage ct: 8 x 48 float4 = 384
    for (int i = tid; i < 384; i += 256) {
        int r = i / 48, q = (i % 48) * 4;
        int b = box0 + r;
        float4 v = make_float4(0, 0, 0, 0);
        if (b < n) v = *(const float4*)&hcat[(size_t)b * 192 + q];
        *(float4*)&ct[r][q] = v;
    }
    __syncthreads();

    // ---- S3: hid = relu(ct @ P1[0:192] + hidg)   [8x192]@[192x128] ----
    {
        int c4 = (tid & 31) * 4;           // 32 col-groups x 4 = 128
        int r  = tid >> 5;                 // 8 rows
        float acc[4] = {};
        #pragma unroll
        for (int k = 0; k < 192; k += 4) {
            float4 a = *(const float4*)&ct[r][k];
            #pragma unroll
            for (int kk = 0; kk < 4; ++kk) {
                float4 w = *(const float4*)&P1[(k + kk) * 128 + c4];
                float av = ((const float*)&a)[kk];
                acc[0] = fmaf(av, w.x, acc[0]);
                acc[1] = fmaf(av, w.y, acc[1]);
                acc[2] = fmaf(av, w.z, acc[2]);
                acc[3] = fmaf(av, w.w, acc[3]);
            }
        }
        float4 hb = *(const float4*)&hidg[c4];
        float4 o;
        o.x = fmaxf(acc[0] + hb.x, 0.0f);
        o.y = fmaxf(acc[1] + hb.y, 0.0f);
        o.z = fmaxf(acc[2] + hb.z, 0.0f);
        o.w = fmaxf(acc[3] + hb.w, 0.0f);
        *(float4*)&hid[r][c4] = o;
    }
    __syncthreads();

    // ---- S4: out = relu(hid @ P2 + bp2)   [8x128]@[128x64] ----
    {
        int c2 = (tid & 31) * 2;           // 32 col-groups x 2 = 64
        int r  = tid >> 5;                 // 8 rows
        float a0 = 0.0f, a1 = 0.0f;
        #pragma unroll
        for (int k = 0; k < 128; k += 4) {
            float4 a = *(const float4*)&hid[r][k];
            #pragma unroll
            for (int kk = 0; kk < 4; ++kk) {
                float2 w = *(const float2*)&P2[(k + kk) * 64 + c2];
                float av = ((const float*)&a)[kk];
                a0 = fmaf(av, w.x, a0);
                a1 = fmaf(av, w.y, a1);
            }
        }
        int row = box0 + r;
        if (row < n) {
            float2 bb = *(const float2*)&bp2[c2];
            float2 o;
            o.x = fmaxf(a0 + bb.x, 0.0f);
            o.y = fmaxf(a1 + bb.y, 0.0f);
            *(float2*)&out[(size_t)row * 64 + c2] = o;
        }
    }
}

extern "C" void kernel_launch(void* const* d_in, const int* in_sizes, int n_in,
                              void* d_out, int out_size, void* d_ws, size_t ws_size,
                              hipStream_t stream) {
    const float* fm    = (const float*)d_in[0];
    const float* boxes = (const float*)d_in[1];
    const float* W1    = (const float*)d_in[2];
    const float* b1    = (const float*)d_in[3];
    const float* W2    = (const float*)d_in[4];
    const float* b2    = (const float*)d_in[5];
    const float* P1    = (const float*)d_in[6];
    const float* bp1   = (const float*)d_in[7];
    const float* P2    = (const float*)d_in[8];
    const float* bp2   = (const float*)d_in[9];
    float* ws = (float*)d_ws;
    __half* fmT     = (__half*)(ws + WS_FMT);
    float* gpartial = ws + WS_GPART;
    float* g        = ws + WS_G;
    int*   perm     = (int*)(ws + WS_PERM);
    float* pooled   = ws + WS_POOL;
    float* out = (float*)d_out;
    int n = in_sizes[1] / 4;   // 4000 boxes
    int nrows = 3 * n;
    float* hidg = ws + WS_POOL + (size_t)nrows * 64;   // [128]
    float* hcat = ws + WS_FMT;                         // reuse fmT region after k_pool

    k_prep<<<961, 256, 0, stream>>>(fm, fmT, gpartial, boxes, perm, n);
    k_pool<<<n, 256, 0, stream>>>(fmT, boxes, perm, gpartial, g, pooled,
                                  W1, b1, W2, b2, P1, bp1, hidg);
    k_head<<<(nrows + 15) / 16, 256, 0, stream>>>(pooled, W1, b1, W2, b2, hcat, nrows);
    k_tail<<<(n + 7) / 8, 256, 0, stream>>>(hcat, hidg, P1, P2, bp2, out, n);
}